// Round 9
// baseline (381.379 us; speedup 1.0000x reference)
//
#include <hip/hip_runtime.h>
#include <math.h>

#define Hd 512
#define Bn 8
#define Sn 8192
#define SB 256            // energy blocks per b (32 rows each)
#define PW (SB * 4)       // partials per b (one per wave)

typedef __attribute__((ext_vector_type(4))) float f32x4;

// ---------------------------------------------------------------------------
// K1: v[b,h] = sum_k hidden[b,k] * W[k,h], partitioned by h-columns.
// grid (16, Bn), block 512 = 16 k-groups x 32 cols. Also zeroes the per-b
// completion counters used by the fused kernel (poison-safe each call).
// ---------------------------------------------------------------------------
__global__ __launch_bounds__(512) void k_proj(const float* __restrict__ hidden,
                                              const float* __restrict__ W,
                                              float* __restrict__ v,
                                              int* __restrict__ cnt) {
    if (blockIdx.x == 0 && blockIdx.y == 0 && threadIdx.x < Bn)
        cnt[threadIdx.x] = 0;

    const int hc = blockIdx.x;        // 0..15
    const int b  = blockIdx.y;
    const int t  = threadIdx.x;
    const int kg = t >> 5;            // 0..15 (k-group: 32 k's each)
    const int c  = t & 31;            // 0..31 (column within stripe)
    const int col = hc * 32 + c;

    __shared__ float hs[Hd];
    __shared__ float partial[16][32];

    hs[t] = hidden[b * Hd + t];
    __syncthreads();

    float acc = 0.f;
    const int k0 = kg * 32;
    #pragma unroll 16
    for (int i = 0; i < 32; ++i)
        acc += hs[k0 + i] * W[(size_t)(k0 + i) * Hd + col];
    partial[kg][c] = acc;
    __syncthreads();

    if (t < 32) {
        float s = partial[0][t];
        #pragma unroll
        for (int j = 1; j < 16; ++j) s += partial[j][t];
        v[b * Hd + hc * 32 + t] = s;
    }
}

// ---------------------------------------------------------------------------
// K2 (fused): e[b,s] = enc[b,s,:].v[b,:] + per-wave (max,sumexp) partials;
// last-arriving block per b (threadfence + atomic counter) merges the 1024
// partials and normalizes out[b,:]. Streaming loop identical to round 7
// (measured at the HBM read ceiling, E ~= 19.8 us).
// ---------------------------------------------------------------------------
__global__ __launch_bounds__(256, 8) void k_energy_fused(
        const float* __restrict__ enc,
        const float* __restrict__ v,
        float* __restrict__ e,
        float2* __restrict__ partials,
        int* __restrict__ cnt,
        float* __restrict__ out) {
    const int sb   = blockIdx.x;
    const int b    = blockIdx.y;
    const int t    = threadIdx.x;
    const int wave = t >> 6, lane = t & 63;

    const f32x4* vp = (const f32x4*)(v + b * Hd);
    const f32x4 v0 = vp[lane];
    const f32x4 v1 = vp[64 + lane];

    const int row0 = sb * 32 + wave * 8;
    const f32x4* base = (const f32x4*)(enc + ((size_t)b * Sn + row0) * Hd);

    float wA, wB;
    #pragma unroll
    for (int g = 0; g < 2; ++g) {
        const int rb = g * 4;
        float p[4];
        #pragma unroll
        for (int r = 0; r < 4; ++r) {
            const f32x4* rowp = base + (size_t)(rb + r) * (Hd / 4);
            const f32x4 a0 = __builtin_nontemporal_load(rowp + lane);
            const f32x4 a1 = __builtin_nontemporal_load(rowp + 64 + lane);
            p[r] = a0.x * v0.x + a0.y * v0.y + a0.z * v0.z + a0.w * v0.w
                 + a1.x * v1.x + a1.y * v1.y + a1.z * v1.z + a1.w * v1.w;
        }
        float s0 = p[0] + __shfl_xor(p[0], 1, 64);
        float s1 = p[1] + __shfl_xor(p[1], 1, 64);
        float s2 = p[2] + __shfl_xor(p[2], 1, 64);
        float s3 = p[3] + __shfl_xor(p[3], 1, 64);
        float t0 = (lane & 1) ? s1 : s0;
        float t1 = (lane & 1) ? s3 : s2;
        t0 += __shfl_xor(t0, 2, 64);
        t1 += __shfl_xor(t1, 2, 64);
        float w = (lane & 2) ? t1 : t0;
        w += __shfl_xor(w, 4, 64);
        w += __shfl_xor(w, 8, 64);
        w += __shfl_xor(w, 16, 64);
        w += __shfl_xor(w, 32, 64);
        if (g == 0) wA = w; else wB = w;
    }

    // per-wave stats: rows replicated every 4 lanes -> offsets 1,2 suffice
    float m = fmaxf(wA, wB);
    m = fmaxf(m, __shfl_xor(m, 1, 64));
    m = fmaxf(m, __shfl_xor(m, 2, 64));
    float s = __expf(wA - m) + __expf(wB - m);
    s += __shfl_xor(s, 1, 64);
    s += __shfl_xor(s, 2, 64);

    if (lane < 8) e[(size_t)b * Sn + row0 + lane] = (lane < 4) ? wA : wB;
    if (lane == 0) partials[(size_t)b * PW + sb * 4 + wave] = make_float2(m, s);

    // ----- completion detection (threadFenceReduction pattern) -----
    __threadfence();                       // release: e + partial visible
    __syncthreads();
    __shared__ int is_last;
    if (t == 0)
        is_last = (atomicAdd(&cnt[b], 1) == SB - 1) ? 1 : 0;
    __syncthreads();
    if (!is_last) return;

    __threadfence();                       // acquire: see all blocks' writes

    // ----- merge this b's 1024 partials -----
    const float2* pp = partials + (size_t)b * PW;
    float M = -INFINITY, L = 0.f;
    #pragma unroll
    for (int i = 0; i < 4; ++i) {
        const float2 q = pp[t + 256 * i];
        const float Mn = fmaxf(M, q.x);
        L = L * __expf(M - Mn) + q.y * __expf(q.x - Mn);
        M = Mn;
    }
    #pragma unroll
    for (int off = 32; off >= 1; off >>= 1) {
        const float Mo = __shfl_xor(M, off, 64);
        const float Lo = __shfl_xor(L, off, 64);
        const float Mn = fmaxf(M, Mo);
        L = L * __expf(M - Mn) + Lo * __expf(Mo - Mn);
        M = Mn;
    }
    __shared__ float redM[4], redL[4];
    if (lane == 0) { redM[wave] = M; redL[wave] = L; }
    __syncthreads();
    M = redM[0]; L = redL[0];
    #pragma unroll
    for (int i = 1; i < 4; ++i) {
        const float Mn = fmaxf(M, redM[i]);
        L = L * __expf(M - Mn) + redL[i] * __expf(redM[i] - Mn);
        M = Mn;
    }
    const float inv = 1.0f / L;

    // ----- normalize out[b,:] (8192 values, float4, coalesced) -----
    const f32x4* ep = (const f32x4*)(e + (size_t)b * Sn);
    f32x4*       op = (f32x4*)(out + (size_t)b * Sn);
    #pragma unroll
    for (int i = 0; i < 8; ++i) {
        const f32x4 x = ep[t + 256 * i];
        f32x4 r;
        r.x = __expf(x.x - M) * inv;
        r.y = __expf(x.y - M) * inv;
        r.z = __expf(x.z - M) * inv;
        r.w = __expf(x.w - M) * inv;
        op[t + 256 * i] = r;
    }
}

// ---------------------------------------------------------------------------
extern "C" void kernel_launch(void* const* d_in, const int* in_sizes, int n_in,
                              void* d_out, int out_size, void* d_ws, size_t ws_size,
                              hipStream_t stream) {
    const float* hidden = (const float*)d_in[0];   // [1,B,H]
    const float* enc    = (const float*)d_in[1];   // [B,S,H]
    const float* W      = (const float*)d_in[2];   // [H,H]
    // d_in[3] (bias) unused: softmax over s is shift-invariant; bias adds a
    // per-b constant c[b] = bias . h[b] that cancels.
    float* out = (float*)d_out;                    // [B,S] f32

    float*  v        = (float*)d_ws;                          // 16 KB
    float2* partials = (float2*)(v + Bn * Hd);                // 64 KB
    float*  e        = (float*)(partials + (size_t)Bn * PW);  // 256 KB
    int*    cnt      = (int*)(e + (size_t)Bn * Sn);           // 32 B

    k_proj        <<<dim3(16, Bn), 512, 0, stream>>>(hidden, W, v, cnt);
    k_energy_fused<<<dim3(SB, Bn), 256, 0, stream>>>(enc, v, e, partials, cnt, out);
}

// Round 10
// 41.902 us; speedup vs baseline: 9.1016x; 9.1016x over previous
//
#include <hip/hip_runtime.h>
#include <math.h>

#define Hd 512
#define Bn 8
#define Sn 8192
#define SB 256            // energy blocks per b (32 rows each)

typedef __attribute__((ext_vector_type(4))) float f32x4;

// ---------------------------------------------------------------------------
// K1: v[b,h] = sum_k hidden[b,k] * W[k,h], partitioned by h-columns.
// grid (16, Bn), block 256 = 8 k-groups x 32 cols. Block (0,0) also zeroes
// the padded per-b arrival counters (poison-safe every call; the proj->efin
// graph edge plus kernel-boundary cache ops make the zeros visible).
// ---------------------------------------------------------------------------
__global__ __launch_bounds__(256) void k_proj(const float* __restrict__ hidden,
                                              const float* __restrict__ W,
                                              float* __restrict__ v,
                                              int* __restrict__ arrive) {
    if (blockIdx.x == 0 && blockIdx.y == 0 && threadIdx.x < Bn)
        arrive[threadIdx.x * 32] = 0;      // 128B stride -> one line per b

    const int hc = blockIdx.x;
    const int b  = blockIdx.y;
    const int t  = threadIdx.x;
    const int kg = t >> 5;
    const int c  = t & 31;
    const int col = hc * 32 + c;

    __shared__ float hs[Hd];
    __shared__ float partial[8][32];

    hs[t]       = hidden[b * Hd + t];
    hs[t + 256] = hidden[b * Hd + t + 256];
    __syncthreads();

    float acc = 0.f;
    const int k0 = kg * 64;
    #pragma unroll 16
    for (int i = 0; i < 64; ++i)
        acc += hs[k0 + i] * W[(size_t)(k0 + i) * Hd + col];
    partial[kg][c] = acc;
    __syncthreads();

    if (t < 32) {
        float s = partial[0][t];
        #pragma unroll
        for (int j = 1; j < 8; ++j) s += partial[j][t];
        v[b * Hd + hc * 32 + t] = s;
    }
}

// ---------------------------------------------------------------------------
// K2 (fused, fence-free): stream energies (identical loop to round 7, at the
// measured memory ceiling) -> memory-side writes of e + per-block (m,l) via
// relaxed agent-scope atomics -> s_waitcnt vmcnt(0) -> one padded per-b
// arrival atomicAdd. Last block per b merges 256 partials and normalizes
// out[b,:], reading e/partials with agent-scope atomic loads (L2-bypass).
// No __threadfence anywhere; no shared counter lines.
// ---------------------------------------------------------------------------
__global__ __launch_bounds__(256, 8) void k_efin(
        const float* __restrict__ enc,
        const float* __restrict__ v,
        float* __restrict__ e,
        unsigned long long* __restrict__ partials,   // packed (m,l) per block
        int* __restrict__ arrive,
        float* __restrict__ out) {
    const int sb   = blockIdx.x;
    const int b    = blockIdx.y;
    const int t    = threadIdx.x;
    const int wave = t >> 6, lane = t & 63;

    const f32x4* vp = (const f32x4*)(v + b * Hd);
    const f32x4 v0 = vp[lane];
    const f32x4 v1 = vp[64 + lane];

    const int row0 = sb * 32 + wave * 8;
    const f32x4* base = (const f32x4*)(enc + ((size_t)b * Sn + row0) * Hd);

    float wA, wB;
    #pragma unroll
    for (int g = 0; g < 2; ++g) {
        const int rb = g * 4;
        float p[4];
        #pragma unroll
        for (int r = 0; r < 4; ++r) {
            const f32x4* rowp = base + (size_t)(rb + r) * (Hd / 4);
            const f32x4 a0 = __builtin_nontemporal_load(rowp + lane);
            const f32x4 a1 = __builtin_nontemporal_load(rowp + 64 + lane);
            p[r] = a0.x * v0.x + a0.y * v0.y + a0.z * v0.z + a0.w * v0.w
                 + a1.x * v1.x + a1.y * v1.y + a1.z * v1.z + a1.w * v1.w;
        }
        float s0 = p[0] + __shfl_xor(p[0], 1, 64);
        float s1 = p[1] + __shfl_xor(p[1], 1, 64);
        float s2 = p[2] + __shfl_xor(p[2], 1, 64);
        float s3 = p[3] + __shfl_xor(p[3], 1, 64);
        float t0 = (lane & 1) ? s1 : s0;
        float t1 = (lane & 1) ? s3 : s2;
        t0 += __shfl_xor(t0, 2, 64);
        t1 += __shfl_xor(t1, 2, 64);
        float w = (lane & 2) ? t1 : t0;
        w += __shfl_xor(w, 4, 64);
        w += __shfl_xor(w, 8, 64);
        w += __shfl_xor(w, 16, 64);
        w += __shfl_xor(w, 32, 64);
        if (g == 0) wA = w; else wB = w;
    }

    // per-wave stats (rows replicated every 4 lanes)
    float m = fmaxf(wA, wB);
    m = fmaxf(m, __shfl_xor(m, 1, 64));
    m = fmaxf(m, __shfl_xor(m, 2, 64));
    float s = __expf(wA - m) + __expf(wB - m);
    s += __shfl_xor(s, 1, 64);
    s += __shfl_xor(s, 2, 64);

    // e written memory-side (relaxed agent atomics: coherent, no fence)
    if (lane < 8)
        atomicExch(&e[(size_t)b * Sn + row0 + lane], (lane < 4) ? wA : wB);

    // block (m,l): merge the 4 wave stats in LDS
    __shared__ float redM[4], redL[4];
    __shared__ int is_last;
    if (lane == 0) { redM[wave] = m; redL[wave] = s; }
    __syncthreads();
    if (t == 0) {
        float M = redM[0], L = redL[0];
        #pragma unroll
        for (int i = 1; i < 4; ++i) {
            const float Mn = fmaxf(M, redM[i]);
            L = L * __expf(M - Mn) + redL[i] * __expf(redM[i] - Mn);
            M = Mn;
        }
        union { float f[2]; unsigned long long u; } pk;
        pk.f[0] = M; pk.f[1] = L;
        atomicExch(&partials[b * SB + sb], pk.u);
        asm volatile("s_waitcnt vmcnt(0)" ::: "memory");  // writes at coherence point
        const int ret = atomicAdd(&arrive[b * 32], 1);
        is_last = (ret == SB - 1) ? 1 : 0;
    }
    __syncthreads();
    if (!is_last) return;

    // ---- winner: merge 256 partials (agent-scope loads bypass stale L2) ----
    union { float f[2]; unsigned long long u; } q;
    q.u = __hip_atomic_load(&partials[b * SB + t], __ATOMIC_RELAXED,
                            __HIP_MEMORY_SCOPE_AGENT);
    float M = q.f[0], L = q.f[1];
    #pragma unroll
    for (int off = 32; off >= 1; off >>= 1) {
        const float Mo = __shfl_xor(M, off, 64);
        const float Lo = __shfl_xor(L, off, 64);
        const float Mn = fmaxf(M, Mo);
        L = L * __expf(M - Mn) + Lo * __expf(Mo - Mn);
        M = Mn;
    }
    __shared__ float fM[4], fL[4];
    if (lane == 0) { fM[wave] = M; fL[wave] = L; }
    __syncthreads();
    M = fM[0]; L = fL[0];
    #pragma unroll
    for (int i = 1; i < 4; ++i) {
        const float Mn = fmaxf(M, fM[i]);
        L = L * __expf(M - Mn) + fL[i] * __expf(fM[i] - Mn);
        M = Mn;
    }
    const float inv = 1.0f / L;

    // ---- winner: normalize out[b,:] (e via agent-scope loads) ----
    const float* eb = e + (size_t)b * Sn;
    float*       ob = out + (size_t)b * Sn;
    #pragma unroll 8
    for (int i = 0; i < 32; ++i) {
        const float x = __hip_atomic_load(&eb[t + 256 * i], __ATOMIC_RELAXED,
                                          __HIP_MEMORY_SCOPE_AGENT);
        ob[t + 256 * i] = __expf(x - M) * inv;
    }
}

// ---------------------------------------------------------------------------
extern "C" void kernel_launch(void* const* d_in, const int* in_sizes, int n_in,
                              void* d_out, int out_size, void* d_ws, size_t ws_size,
                              hipStream_t stream) {
    const float* hidden = (const float*)d_in[0];   // [1,B,H]
    const float* enc    = (const float*)d_in[1];   // [B,S,H]
    const float* W      = (const float*)d_in[2];   // [H,H]
    // d_in[3] (bias) unused: softmax over s is shift-invariant; bias adds a
    // per-b constant c[b] = bias . h[b] that cancels.
    float* out = (float*)d_out;                    // [B,S] f32

    float*              v        = (float*)d_ws;                       // 16 KB
    unsigned long long* partials = (unsigned long long*)(v + Bn * Hd); // 16 KB
    float*              e        = (float*)(partials + Bn * SB);       // 256 KB
    int*                arrive   = (int*)(e + (size_t)Bn * Sn);        // 1 KB padded

    k_proj<<<dim3(16, Bn), 256, 0, stream>>>(hidden, W, v, arrive);
    k_efin<<<dim3(SB, Bn), 256, 0, stream>>>(enc, v, e, partials, arrive, out);
}

// Round 11
// 35.064 us; speedup vs baseline: 10.8768x; 1.1950x over previous
//
#include <hip/hip_runtime.h>
#include <math.h>

#define Hd 512
#define Bn 8
#define Sn 8192
#define SB 256            // energy blocks per b (32 rows each)
#define PW (SB * 4)       // partials per b (one per wave)

typedef __attribute__((ext_vector_type(4))) float f32x4;

// ---------------------------------------------------------------------------
// K1: v[b,h] = sum_k hidden[b,k] * W[k,h], partitioned by h-columns.
// grid (16, Bn), block 512 = 16 k-groups x 32 cols (as in round 7).
// ---------------------------------------------------------------------------
__global__ __launch_bounds__(512) void k_proj(const float* __restrict__ hidden,
                                              const float* __restrict__ W,
                                              float* __restrict__ v) {
    const int hc = blockIdx.x;        // 0..15
    const int b  = blockIdx.y;
    const int t  = threadIdx.x;
    const int kg = t >> 5;            // 0..15 (k-group: 32 k's each)
    const int c  = t & 31;            // 0..31 (column within stripe)
    const int col = hc * 32 + c;

    __shared__ float hs[Hd];
    __shared__ float partial[16][32];

    hs[t] = hidden[b * Hd + t];
    __syncthreads();

    float acc = 0.f;
    const int k0 = kg * 32;
    #pragma unroll 16
    for (int i = 0; i < 32; ++i)
        acc += hs[k0 + i] * W[(size_t)(k0 + i) * Hd + col];
    partial[kg][c] = acc;
    __syncthreads();

    if (t < 32) {
        float s = partial[0][t];
        #pragma unroll
        for (int j = 1; j < 16; ++j) s += partial[j][t];
        v[b * Hd + hc * 32 + t] = s;
    }
}

// ---------------------------------------------------------------------------
// K2: e[b,s] = enc[b,s,:] . v[b,:]  + per-WAVE (max, sum-exp) partial.
// grid (SB, Bn), block 256 (4 waves); 8 rows per wave.
// Changes vs round 7: (a) NO nontemporal hints -> let the 134 MB enc stay
// Infinity-Cache-resident across graph replays; (b) all 16 loads issued
// before any reduction (2x outstanding requests per wave);
// (c) launch_bounds(256,5): VGPR cap ~102 for the 16 live f32x4 buffers.
// ---------------------------------------------------------------------------
__global__ __launch_bounds__(256, 5) void k_energy(const float* __restrict__ enc,
                                                   const float* __restrict__ v,
                                                   float* __restrict__ e,
                                                   float2* __restrict__ partials) {
    const int sb   = blockIdx.x;
    const int b    = blockIdx.y;
    const int wave = threadIdx.x >> 6, lane = threadIdx.x & 63;

    const f32x4* vp = (const f32x4*)(v + b * Hd);
    const f32x4 v0 = vp[lane];
    const f32x4 v1 = vp[64 + lane];

    const int row0 = sb * 32 + wave * 8;
    const f32x4* base = (const f32x4*)(enc + ((size_t)b * Sn + row0) * Hd);

    // ---- all 16 loads in flight before any consumption ----
    f32x4 A[8], C[8];
    #pragma unroll
    for (int r = 0; r < 8; ++r) {
        A[r] = base[(size_t)r * (Hd / 4) + lane];
        C[r] = base[(size_t)r * (Hd / 4) + 64 + lane];
    }

    float p[8];
    #pragma unroll
    for (int r = 0; r < 8; ++r)
        p[r] = A[r].x * v0.x + A[r].y * v0.y + A[r].z * v0.z + A[r].w * v0.w
             + C[r].x * v1.x + C[r].y * v1.y + C[r].z * v1.z + C[r].w * v1.w;

    // ---- two packed 4-row reduces (lane l<4 ends with row rb+l) ----
    float wg[2];
    #pragma unroll
    for (int g = 0; g < 2; ++g) {
        const int rb = g * 4;
        float s0 = p[rb + 0] + __shfl_xor(p[rb + 0], 1, 64);
        float s1 = p[rb + 1] + __shfl_xor(p[rb + 1], 1, 64);
        float s2 = p[rb + 2] + __shfl_xor(p[rb + 2], 1, 64);
        float s3 = p[rb + 3] + __shfl_xor(p[rb + 3], 1, 64);
        float t0 = (lane & 1) ? s1 : s0;
        float t1 = (lane & 1) ? s3 : s2;
        t0 += __shfl_xor(t0, 2, 64);
        t1 += __shfl_xor(t1, 2, 64);
        float w = (lane & 2) ? t1 : t0;
        w += __shfl_xor(w, 4, 64);
        w += __shfl_xor(w, 8, 64);
        w += __shfl_xor(w, 16, 64);
        w += __shfl_xor(w, 32, 64);
        wg[g] = w;
    }
    const float wA = wg[0], wB = wg[1];

    // per-wave stats: rows replicated every 4 lanes -> offsets 1,2 suffice
    float m = fmaxf(wA, wB);
    m = fmaxf(m, __shfl_xor(m, 1, 64));
    m = fmaxf(m, __shfl_xor(m, 2, 64));
    float s = __expf(wA - m) + __expf(wB - m);
    s += __shfl_xor(s, 1, 64);
    s += __shfl_xor(s, 2, 64);

    if (lane < 8) e[(size_t)b * Sn + row0 + lane] = (lane < 4) ? wA : wB;
    if (lane == 0) partials[(size_t)b * PW + sb * 4 + wave] = make_float2(m, s);
}

// ---------------------------------------------------------------------------
// K3: out[b,j] = exp(e[b,j] - M_b) / L_b.  grid (16, Bn), block 512.
// Each lane loads 16 of the 1024 partials, register-tree LSE merge (depth 4),
// then a 6-step butterfly across the wave. Identical to round 7.
// ---------------------------------------------------------------------------
__global__ __launch_bounds__(512) void k_finalize(const float* __restrict__ e,
                                                  const float2* __restrict__ partials,
                                                  float* __restrict__ out) {
    const int b    = blockIdx.y;
    const int t    = threadIdx.x;
    const int lane = t & 63;

    const float2* pp = partials + (size_t)b * PW;
    float m[16], l[16];
    #pragma unroll
    for (int i = 0; i < 16; ++i) {
        const float2 q = pp[lane + 64 * i];
        m[i] = q.x; l[i] = q.y;
    }
    #pragma unroll
    for (int st = 8; st >= 1; st >>= 1) {
        #pragma unroll
        for (int i = 0; i < st; ++i) {
            const float Mn = fmaxf(m[i], m[i + st]);
            l[i] = l[i] * __expf(m[i] - Mn) + l[i + st] * __expf(m[i + st] - Mn);
            m[i] = Mn;
        }
    }
    float M = m[0], L = l[0];
    #pragma unroll
    for (int off = 32; off >= 1; off >>= 1) {
        const float Mo = __shfl_xor(M, off, 64);
        const float Lo = __shfl_xor(L, off, 64);
        const float Mn = fmaxf(M, Mo);
        L = L * __expf(M - Mn) + Lo * __expf(Mo - Mn);
        M = Mn;
    }
    const float inv = 1.0f / L;

    const size_t j = (size_t)b * Sn + blockIdx.x * 512 + t;
    out[j] = __expf(e[j] - M) * inv;
}

// ---------------------------------------------------------------------------
extern "C" void kernel_launch(void* const* d_in, const int* in_sizes, int n_in,
                              void* d_out, int out_size, void* d_ws, size_t ws_size,
                              hipStream_t stream) {
    const float* hidden = (const float*)d_in[0];   // [1,B,H]
    const float* enc    = (const float*)d_in[1];   // [B,S,H]
    const float* W      = (const float*)d_in[2];   // [H,H]
    // d_in[3] (bias) unused: softmax over s is shift-invariant; bias adds a
    // per-b constant c[b] = bias . h[b] that cancels.
    float* out = (float*)d_out;                    // [B,S] f32

    float*  v        = (float*)d_ws;               // Bn*Hd floats (16 KB)
    float2* partials = (float2*)(v + Bn * Hd);     // Bn*PW float2 (64 KB)
    float*  e        = (float*)(partials + (size_t)Bn * PW); // Bn*Sn floats

    k_proj    <<<dim3(16, Bn), 512, 0, stream>>>(hidden, W, v);
    k_energy  <<<dim3(SB, Bn), 256, 0, stream>>>(enc, v, e, partials);
    k_finalize<<<dim3(16, Bn), 512, 0, stream>>>(e, partials, out);
}